// Round 10
// baseline (540.878 us; speedup 1.0000x reference)
//
#include <hip/hip_runtime.h>
#include <hip/hip_cooperative_groups.h>
#include <cstdint>
#include <cstddef>

namespace cg = cooperative_groups;

#define DEV __device__ __forceinline__

typedef __attribute__((ext_vector_type(8))) short bf16x8;
typedef __attribute__((ext_vector_type(4))) float f32x4;

constexpr int N_  = 16384;
constexpr int D_  = 1024;
constexpr int E_  = 65536;
constexpr int ET_ = E_ + N_;   // edges incl. self loops
constexpr int H_  = 8;
constexpr int C_  = 512;
constexpr int F_  = 4096;      // H_*C_
constexpr int ZS_ = 48;        // [al_s 0..7 | al_d 8..15 | z0 16..23 | z1 24..31 | zd 32..39 | pad]
constexpr int KSPLIT = 4;
constexpr int NVB = 2048;      // V-build blocks (fallback prep)
constexpr int GB_ = 1024;      // mega grid blocks
constexpr int GT_ = GB_ * 256; // mega total threads

// ---------- helpers ----------
DEV unsigned short f2bf(float f){
  unsigned u = __float_as_uint(f);
  unsigned r = u + 0x7FFFu + ((u >> 16) & 1u); // RNE
  return (unsigned short)(r >> 16);
}
DEV float lrelu(float x){ return x >= 0.f ? x : 0.2f * x; }
DEV float waveSum(float v){
  #pragma unroll
  for (int o = 32; o > 0; o >>= 1) v += __shfl_xor(v, o);
  return v;
}
DEV int eSRC(const int* ei, int e){ return e < E_ ? ei[e]      : e - E_; }
DEV int eDST(const int* ei, int e){ return e < E_ ? ei[E_ + e] : e - E_; }

// ---------- shared phase bodies ----------
DEV void vbuild_one(int id, int lane,
                    const float* __restrict__ W1s, const float* __restrict__ W1d,
                    const float* __restrict__ a1s, const float* __restrict__ a1d,
                    const float* __restrict__ W2s, const float* __restrict__ W2d,
                    float a2d0, float a2d1, unsigned short* __restrict__ Vb){
  int d = id >> 3, h = id & 7;
  float sa = 0.f, sb = 0.f, s0 = 0.f, s1 = 0.f, sd = 0.f;
  #pragma unroll
  for (int i = 0; i < C_ / 64; i++){
    int c = i * 64 + lane;
    int gc = h * C_ + c;
    float ws  = W1s[(size_t)d * F_ + gc];
    float wdv = W1d[(size_t)d * F_ + gc];
    sa += ws * a1s[gc]; sb += wdv * a1d[gc];
    float2 w2 = *reinterpret_cast<const float2*>(W2s + (size_t)gc * 2);
    float2 wx = *reinterpret_cast<const float2*>(W2d + (size_t)gc * 2);
    s0 += ws * w2.x; s1 += ws * w2.y;
    sd += ws * (wx.x * a2d0 + wx.y * a2d1);
  }
  sa = waveSum(sa); sb = waveSum(sb);
  s0 = waveSum(s0); s1 = waveSum(s1); sd = waveSum(sd);
  if (lane == 0){
    int kc = d >> 5, ks = (d >> 3) & 3, ii = d & 7;
    auto put = [&](int jj, float v){
      int tt = jj >> 4, j = jj & 15;
      Vb[((size_t)(tt * 32 + kc) * 64 + ks * 16 + j) * 8 + ii] = f2bf(v);
    };
    put(h, sa); put(8 + h, sb); put(16 + h, s0); put(24 + h, s1); put(32 + h, sd);
  }
}

DEV void cb_one(int lane, const float* __restrict__ b1,
                const float* __restrict__ W2s, const float* __restrict__ W2d,
                float a2d0, float a2d1, float* __restrict__ cb){
  float p0 = 0.f, p1 = 0.f, pd = 0.f;
  #pragma unroll 4
  for (int i = 0; i < F_ / 64; i++){
    int k = i * 64 + lane;
    float b = b1[k];
    float2 w2 = *reinterpret_cast<const float2*>(W2s + (size_t)k * 2);
    float2 wx = *reinterpret_cast<const float2*>(W2d + (size_t)k * 2);
    p0 += b * w2.x; p1 += b * w2.y; pd += b * (wx.x * a2d0 + wx.y * a2d1);
  }
  p0 = waveSum(p0); p1 = waveSum(p1); pd = waveSum(pd);
  if (lane == 0){ cb[0] = p0; cb[1] = p1; cb[2] = pd; }
}

DEV void nodemfma_one(int ngrp, int kh, int lane, const float* __restrict__ X,
                      const unsigned short* __restrict__ Vb, float* __restrict__ Z){
  int n0 = ngrp * 16;
  int row = lane & 15, ks = lane >> 4;
  f32x4 ac0 = {0.f,0.f,0.f,0.f}, ac1 = ac0, ac2 = ac0;
  const float* xp = X + (size_t)(n0 + row) * D_ + ks * 8;
  constexpr int KC = 32 / KSPLIT;
  #pragma unroll 2
  for (int kk = 0; kk < KC; kk++){
    int kc = kh * KC + kk;
    float4 xa = *reinterpret_cast<const float4*>(xp + kc * 32);
    float4 xb = *reinterpret_cast<const float4*>(xp + kc * 32 + 4);
    bf16x8 a;
    a[0] = (short)f2bf(xa.x); a[1] = (short)f2bf(xa.y);
    a[2] = (short)f2bf(xa.z); a[3] = (short)f2bf(xa.w);
    a[4] = (short)f2bf(xb.x); a[5] = (short)f2bf(xb.y);
    a[6] = (short)f2bf(xb.z); a[7] = (short)f2bf(xb.w);
    bf16x8 b0 = *reinterpret_cast<const bf16x8*>(&Vb[((size_t)( 0 + kc) * 64 + lane) * 8]);
    bf16x8 b1 = *reinterpret_cast<const bf16x8*>(&Vb[((size_t)(32 + kc) * 64 + lane) * 8]);
    bf16x8 b2 = *reinterpret_cast<const bf16x8*>(&Vb[((size_t)(64 + kc) * 64 + lane) * 8]);
    ac0 = __builtin_amdgcn_mfma_f32_16x16x32_bf16(a, b0, ac0, 0, 0, 0);
    ac1 = __builtin_amdgcn_mfma_f32_16x16x32_bf16(a, b1, ac1, 0, 0, 0);
    ac2 = __builtin_amdgcn_mfma_f32_16x16x32_bf16(a, b2, ac2, 0, 0, 0);
  }
  #pragma unroll
  for (int r = 0; r < 4; r++){
    int n = n0 + ks * 4 + r;
    atomicAdd(&Z[(size_t)n * ZS_ +  0 + row], ac0[r]);
    atomicAdd(&Z[(size_t)n * ZS_ + 16 + row], ac1[r]);
    atomicAdd(&Z[(size_t)n * ZS_ + 32 + row], ac2[r]);
  }
}

DEV void edge1_one(int t, const int* __restrict__ ei, const float* __restrict__ Z,
                   float* __restrict__ den1, float* __restrict__ a0,
                   float* __restrict__ a1, float* __restrict__ ad){
  int e = t >> 3, h = t & 7;
  int s = eSRC(ei, e), d = eDST(ei, e);
  const float* zs = Z + (size_t)s * ZS_;
  float ev = expf(lrelu(zs[h] + Z[(size_t)d * ZS_ + 8 + h]));
  int o = d * 8 + h;
  atomicAdd(&den1[o], ev);
  atomicAdd(&a0[o], ev * zs[16 + h]);
  atomicAdd(&a1[o], ev * zs[24 + h]);
  atomicAdd(&ad[o], ev * zs[32 + h]);
}

DEV void edge2_one(int e, const int* __restrict__ ei, const float* __restrict__ den1,
                   const float* __restrict__ a0, const float* __restrict__ a1,
                   const float* __restrict__ ad, const float* __restrict__ cb,
                   const float* __restrict__ a2s, float* __restrict__ den2,
                   float* __restrict__ o0, float* __restrict__ o1){
  int s = eSRC(ei, e), d = eDST(ei, e);
  float4 dsa = *reinterpret_cast<const float4*>(den1 + (size_t)s * 8);
  float4 dsb = *reinterpret_cast<const float4*>(den1 + (size_t)s * 8 + 4);
  float4 a0a = *reinterpret_cast<const float4*>(a0 + (size_t)s * 8);
  float4 a0b = *reinterpret_cast<const float4*>(a0 + (size_t)s * 8 + 4);
  float4 a1a = *reinterpret_cast<const float4*>(a1 + (size_t)s * 8);
  float4 a1b = *reinterpret_cast<const float4*>(a1 + (size_t)s * 8 + 4);
  float i0 = 1.f/(dsa.x+1e-16f), i1 = 1.f/(dsa.y+1e-16f);
  float i2 = 1.f/(dsa.z+1e-16f), i3 = 1.f/(dsa.w+1e-16f);
  float i4 = 1.f/(dsb.x+1e-16f), i5 = 1.f/(dsb.y+1e-16f);
  float i6 = 1.f/(dsb.z+1e-16f), i7 = 1.f/(dsb.w+1e-16f);
  float v0 = cb[0] + a0a.x*i0 + a0a.y*i1 + a0a.z*i2 + a0a.w*i3
                   + a0b.x*i4 + a0b.y*i5 + a0b.z*i6 + a0b.w*i7;
  float v1 = cb[1] + a1a.x*i0 + a1a.y*i1 + a1a.z*i2 + a1a.w*i3
                   + a1b.x*i4 + a1b.y*i5 + a1b.z*i6 + a1b.w*i7;
  float4 dda = *reinterpret_cast<const float4*>(den1 + (size_t)d * 8);
  float4 ddb = *reinterpret_cast<const float4*>(den1 + (size_t)d * 8 + 4);
  float4 ada = *reinterpret_cast<const float4*>(ad + (size_t)d * 8);
  float4 adb = *reinterpret_cast<const float4*>(ad + (size_t)d * 8 + 4);
  float vd = cb[2] + ada.x/(dda.x+1e-16f) + ada.y/(dda.y+1e-16f)
                   + ada.z/(dda.z+1e-16f) + ada.w/(dda.w+1e-16f)
                   + adb.x/(ddb.x+1e-16f) + adb.y/(ddb.y+1e-16f)
                   + adb.z/(ddb.z+1e-16f) + adb.w/(ddb.w+1e-16f);
  float als = v0 * a2s[0] + v1 * a2s[1];
  float ev = expf(lrelu(als + vd));
  atomicAdd(&den2[d], ev);
  atomicAdd(&o0[d], ev * v0);
  atomicAdd(&o1[d], ev * v1);
}

// ---------- parameter block ----------
struct P {
  const float *x; const int *ei;
  const float *W1s, *W1d, *a1s, *a1d, *b1, *W2s, *W2d, *a2s, *a2d, *b2;
  float *Z, *den1, *a0, *a1, *ad, *den2, *o0, *o1;
  unsigned short *Vb; float *cb; float *out; int n16;
};

// ---------- cooperative mega-kernel ----------
__global__ __launch_bounds__(256, 4) void mega(P p){
  cg::grid_group grid = cg::this_grid();
  int t = threadIdx.x;
  int gtid = blockIdx.x * 256 + t;
  int w = t >> 6, lane = t & 63;
  int gw = blockIdx.x * 4 + w;              // 0..4095

  // ---- phase A: zero region + build V + cb ----
  {
    uint4 z = {0u,0u,0u,0u};
    uint4* zr = (uint4*)p.Z;
    for (int i = gtid; i < p.n16; i += GT_) zr[i] = z;
    float a2d0 = p.a2d[0], a2d1 = p.a2d[1];
    vbuild_one(gw * 2,     lane, p.W1s, p.W1d, p.a1s, p.a1d, p.W2s, p.W2d, a2d0, a2d1, p.Vb);
    vbuild_one(gw * 2 + 1, lane, p.W1s, p.W1d, p.a1s, p.a1d, p.W2s, p.W2d, a2d0, a2d1, p.Vb);
    if (gw == 0) cb_one(lane, p.b1, p.W2s, p.W2d, a2d0, a2d1, p.cb);
  }
  grid.sync();

  // ---- phase B: Z = x @ V ----
  nodemfma_one(gw >> 2, gw & 3, lane, p.x, p.Vb, p.Z);
  grid.sync();

  // ---- phase C: layer-1 edge pass ----
  for (int i = gtid; i < ET_ * H_; i += GT_)
    edge1_one(i, p.ei, p.Z, p.den1, p.a0, p.a1, p.ad);
  grid.sync();

  // ---- phase D: layer-2 edge pass ----
  if (gtid < ET_)
    edge2_one(gtid, p.ei, p.den1, p.a0, p.a1, p.ad, p.cb, p.a2s, p.den2, p.o0, p.o1);
  grid.sync();

  // ---- phase E: final division + bias ----
  if (gtid < N_){
    float inv = 1.f / (p.den2[gtid] + 1e-16f);
    p.out[2 * gtid]     = p.o0[gtid] * inv + p.b2[0];
    p.out[2 * gtid + 1] = p.o1[gtid] * inv + p.b2[1];
  }
}

// ---------- fallback kernels (round-9 proven path) ----------
__global__ __launch_bounds__(256) void prep(
    const float* __restrict__ W1s, const float* __restrict__ W1d,
    const float* __restrict__ a1s, const float* __restrict__ a1d,
    const float* __restrict__ W2s, const float* __restrict__ W2d,
    const float* __restrict__ a2d, const float* __restrict__ b1,
    unsigned short* __restrict__ Vb, float* __restrict__ cb,
    uint4* __restrict__ zr, int n16){
  int t = threadIdx.x;
  int bx = blockIdx.x;
  if (bx < NVB){
    float a2d0 = a2d[0], a2d1 = a2d[1];
    vbuild_one(bx * 4 + (t >> 6), t & 63, W1s, W1d, a1s, a1d, W2s, W2d, a2d0, a2d1, Vb);
  } else if (bx == NVB){
    if (t < 64) cb_one(t, b1, W2s, W2d, a2d[0], a2d[1], cb);
  } else {
    int i = (bx - NVB - 1) * 256 + t;
    if (i < n16){ uint4 z = {0u, 0u, 0u, 0u}; zr[i] = z; }
  }
}

__global__ __launch_bounds__(64) void node_mfma(const float* __restrict__ X,
                                                const unsigned short* __restrict__ Vb,
                                                float* __restrict__ Z){
  nodemfma_one(blockIdx.x, blockIdx.y, threadIdx.x, X, Vb, Z);
}

__global__ void edge1(const int* __restrict__ ei, const float* __restrict__ Z,
                      float* __restrict__ den1, float* __restrict__ a0,
                      float* __restrict__ a1, float* __restrict__ ad){
  int t = blockIdx.x * blockDim.x + threadIdx.x;
  if (t < ET_ * H_) edge1_one(t, ei, Z, den1, a0, a1, ad);
}

__global__ void edge2(const int* __restrict__ ei, const float* __restrict__ den1,
                      const float* __restrict__ a0, const float* __restrict__ a1,
                      const float* __restrict__ ad, const float* __restrict__ cb,
                      const float* __restrict__ a2s,
                      float* __restrict__ den2, float* __restrict__ o0,
                      float* __restrict__ o1){
  int e = blockIdx.x * blockDim.x + threadIdx.x;
  if (e < ET_) edge2_one(e, ei, den1, a0, a1, ad, cb, a2s, den2, o0, o1);
}

__global__ void node_out(const float* __restrict__ den2, const float* __restrict__ o0,
                         const float* __restrict__ o1, const float* __restrict__ b2,
                         float* __restrict__ out){
  int n = blockIdx.x * blockDim.x + threadIdx.x;
  if (n >= N_) return;
  float inv = 1.f / (den2[n] + 1e-16f);
  out[2 * n]     = o0[n] * inv + b2[0];
  out[2 * n + 1] = o1[n] * inv + b2[1];
}

// ---------- host ----------
extern "C" void kernel_launch(void* const* d_in, const int* in_sizes, int n_in,
                              void* d_out, int out_size, void* d_ws, size_t ws_size,
                              hipStream_t stream){
  const float* x   = (const float*)d_in[0];
  const int*   ei  = (const int*)  d_in[1];
  const float* W1s = (const float*)d_in[2];
  const float* W1d = (const float*)d_in[3];
  const float* a1s = (const float*)d_in[4];
  const float* a1d = (const float*)d_in[5];
  const float* b1  = (const float*)d_in[6];
  const float* W2s = (const float*)d_in[7];
  const float* W2d = (const float*)d_in[8];
  const float* a2s = (const float*)d_in[9];
  const float* a2d = (const float*)d_in[10];
  const float* b2  = (const float*)d_in[11];
  float* out = (float*)d_out;

  char* p = (char*)d_ws;
  auto alloc = [&](size_t bytes) -> void* {
    void* r = (void*)p;
    p += (bytes + 255) & ~(size_t)255;
    return r;
  };
  // ---- contiguous zero region ----
  float* Z     = (float*)alloc((size_t)N_ * ZS_ * 4);      // 3 MB
  float* den1  = (float*)alloc((size_t)N_ * H_ * 4);       // 512 KB
  float* a0    = (float*)alloc((size_t)N_ * H_ * 4);
  float* a1    = (float*)alloc((size_t)N_ * H_ * 4);
  float* ad    = (float*)alloc((size_t)N_ * H_ * 4);
  float* den2  = (float*)alloc((size_t)N_ * 4);            // 64 KB
  float* o0    = (float*)alloc((size_t)N_ * 4);
  float* o1    = (float*)alloc((size_t)N_ * 4);
  // ---- end zero region ----
  unsigned short* Vb = (unsigned short*)alloc((size_t)3 * 32 * 64 * 8 * 2); // 96 KB
  float* cb    = (float*)alloc(256);

  size_t zrBytes = (size_t)((char*)Vb - (char*)Z);
  int n16 = (int)(zrBytes / 16);

  P hp = { x, ei, W1s, W1d, a1s, a1d, b1, W2s, W2d, a2s, a2d, b2,
           Z, den1, a0, a1, ad, den2, o0, o1, Vb, cb, out, n16 };
  void* args[] = { &hp };
  hipError_t err = hipLaunchCooperativeKernel((const void*)mega, dim3(GB_), dim3(256),
                                              args, 0, stream);
  if (err != hipSuccess){
    // fallback: proven 5-kernel chain
    int nzb = (n16 + 255) / 256;
    prep<<<dim3(NVB + 1 + nzb), dim3(256), 0, stream>>>(W1s, W1d, a1s, a1d, W2s, W2d,
                                                        a2d, b1, Vb, cb, (uint4*)Z, n16);
    node_mfma<<<dim3(N_ / 16, KSPLIT), dim3(64), 0, stream>>>(x, Vb, Z);
    edge1<<<dim3(ET_ * H_ / 256), dim3(256), 0, stream>>>(ei, Z, den1, a0, a1, ad);
    edge2<<<dim3(ET_ / 256), dim3(256), 0, stream>>>(ei, den1, a0, a1, ad, cb, a2s,
                                                     den2, o0, o1);
    node_out<<<dim3(N_ / 256), dim3(256), 0, stream>>>(den2, o0, o1, b2, out);
  }
}

// Round 11
// 74.980 us; speedup vs baseline: 7.2137x; 7.2137x over previous
//
#include <hip/hip_runtime.h>
#include <cstdint>
#include <cstddef>

#define DEV __device__ __forceinline__

typedef __attribute__((ext_vector_type(8))) short bf16x8;
typedef __attribute__((ext_vector_type(4))) float f32x4;

constexpr int N_  = 16384;
constexpr int D_  = 1024;
constexpr int E_  = 65536;
constexpr int ET_ = E_ + N_;   // edges incl. self loops
constexpr int H_  = 8;
constexpr int C_  = 512;
constexpr int F_  = 4096;      // H_*C_
constexpr int KSPLIT = 4;
constexpr int ZS4 = KSPLIT * 48;  // per-node: 4 slices x [al_s 0..7|al_d 8..15|z0|z1|zd|pad]
constexpr int NVB = 2048;      // V-build blocks in prep

// ---------- helpers ----------
DEV unsigned short f2bf(float f){
  unsigned u = __float_as_uint(f);
  unsigned r = u + 0x7FFFu + ((u >> 16) & 1u); // RNE
  return (unsigned short)(r >> 16);
}
DEV float lrelu(float x){ return x >= 0.f ? x : 0.2f * x; }
DEV float waveSum(float v){
  #pragma unroll
  for (int o = 32; o > 0; o >>= 1) v += __shfl_xor(v, o);
  return v;
}
DEV int eSRC(const int* ei, int e){ return e < E_ ? ei[e]      : e - E_; }
DEV int eDST(const int* ei, int e){ return e < E_ ? ei[E_ + e] : e - E_; }
DEV f32x4 ldnt4(const float* p){
  return __builtin_nontemporal_load(reinterpret_cast<const f32x4*>(p));
}

// ---------- kernel 1: prep = build V (MFMA-B-frag) + cb + zero region ----------
// col jj of V: jj=h: W1s_h.a1s[h] | 8+h: W1d_h.a1d[h] | 16+h: W1s_h.W2s[:,0]
//              24+h: W1s_h.W2s[:,1] | 32+h: W1s_h.wd2  (wd2 inline from W2d)
// Vb[((tt*32+kc)*64 + ks*16 + j)*8 + i], tt=jj>>4, j=jj&15, kc=d>>5, ks=(d>>3)&3, i=d&7
__global__ __launch_bounds__(256) void prep(
    const float* __restrict__ W1s, const float* __restrict__ W1d,
    const float* __restrict__ a1s, const float* __restrict__ a1d,
    const float* __restrict__ W2s, const float* __restrict__ W2d,
    const float* __restrict__ a2d, const float* __restrict__ b1,
    unsigned short* __restrict__ Vb, float* __restrict__ cb,
    uint4* __restrict__ zr, int n16){
  int t = threadIdx.x;
  int bx = blockIdx.x;
  if (bx < NVB){
    int id = bx * 4 + (t >> 6);            // 0..8191
    int lane = t & 63;
    int d = id >> 3, h = id & 7;
    float a2d0 = a2d[0], a2d1 = a2d[1];
    float sa = 0.f, sb = 0.f, s0 = 0.f, s1 = 0.f, sd = 0.f;
    #pragma unroll
    for (int i = 0; i < C_ / 64; i++){
      int c = i * 64 + lane;
      int gc = h * C_ + c;
      float ws  = __builtin_nontemporal_load(&W1s[(size_t)d * F_ + gc]);
      float wdv = __builtin_nontemporal_load(&W1d[(size_t)d * F_ + gc]);
      sa += ws * a1s[gc]; sb += wdv * a1d[gc];
      float2 w2 = *reinterpret_cast<const float2*>(W2s + (size_t)gc * 2);
      float2 wx = *reinterpret_cast<const float2*>(W2d + (size_t)gc * 2);
      s0 += ws * w2.x; s1 += ws * w2.y;
      sd += ws * (wx.x * a2d0 + wx.y * a2d1);
    }
    sa = waveSum(sa); sb = waveSum(sb);
    s0 = waveSum(s0); s1 = waveSum(s1); sd = waveSum(sd);
    if (lane == 0){
      int kc = d >> 5, ks = (d >> 3) & 3, ii = d & 7;
      auto put = [&](int jj, float v){
        int tt = jj >> 4, j = jj & 15;
        Vb[((size_t)(tt * 32 + kc) * 64 + ks * 16 + j) * 8 + ii] = f2bf(v);
      };
      put(h, sa); put(8 + h, sb); put(16 + h, s0); put(24 + h, s1); put(32 + h, sd);
    }
  } else if (bx == NVB){
    // cb = (b1.W2s[:,0], b1.W2s[:,1], b1.wd2)
    __shared__ float red[3][4];
    int w = t >> 6, lane = t & 63;
    float a2d0 = a2d[0], a2d1 = a2d[1];
    float p0 = 0.f, p1 = 0.f, pd = 0.f;
    for (int k = t; k < F_; k += 256){
      float b = b1[k];
      float2 w2 = *reinterpret_cast<const float2*>(W2s + (size_t)k * 2);
      float2 wx = *reinterpret_cast<const float2*>(W2d + (size_t)k * 2);
      p0 += b * w2.x; p1 += b * w2.y; pd += b * (wx.x * a2d0 + wx.y * a2d1);
    }
    p0 = waveSum(p0); p1 = waveSum(p1); pd = waveSum(pd);
    if (lane == 0){ red[0][w] = p0; red[1][w] = p1; red[2][w] = pd; }
    __syncthreads();
    if (t == 0){
      cb[0] = red[0][0] + red[0][1] + red[0][2] + red[0][3];
      cb[1] = red[1][0] + red[1][1] + red[1][2] + red[1][3];
      cb[2] = red[2][0] + red[2][1] + red[2][2] + red[2][3];
    }
  } else {
    int i = (bx - NVB - 1) * 256 + t;
    if (i < n16){ uint4 z = {0u, 0u, 0u, 0u}; zr[i] = z; }
  }
}

// ---------- kernel 2: Z4[n][kh][0..47] = x[n] @ V (plain stores, slice per kh) ----------
__global__ __launch_bounds__(64) void node_mfma(const float* __restrict__ X,
                                                const unsigned short* __restrict__ Vb,
                                                float* __restrict__ Z4){
  int lane = threadIdx.x;
  int n0 = blockIdx.x * 16;
  int kh = blockIdx.y;                       // 0..KSPLIT-1
  int row = lane & 15, ks = lane >> 4;
  f32x4 ac0 = {0.f,0.f,0.f,0.f}, ac1 = ac0, ac2 = ac0;
  const float* xp = X + (size_t)(n0 + row) * D_ + ks * 8;
  constexpr int KC = 32 / KSPLIT;
  #pragma unroll 2
  for (int kk = 0; kk < KC; kk++){
    int kc = kh * KC + kk;
    f32x4 xa = ldnt4(xp + kc * 32);
    f32x4 xb = ldnt4(xp + kc * 32 + 4);
    bf16x8 a;
    a[0] = (short)f2bf(xa[0]); a[1] = (short)f2bf(xa[1]);
    a[2] = (short)f2bf(xa[2]); a[3] = (short)f2bf(xa[3]);
    a[4] = (short)f2bf(xb[0]); a[5] = (short)f2bf(xb[1]);
    a[6] = (short)f2bf(xb[2]); a[7] = (short)f2bf(xb[3]);
    bf16x8 b0 = *reinterpret_cast<const bf16x8*>(&Vb[((size_t)( 0 + kc) * 64 + lane) * 8]);
    bf16x8 b1 = *reinterpret_cast<const bf16x8*>(&Vb[((size_t)(32 + kc) * 64 + lane) * 8]);
    bf16x8 b2 = *reinterpret_cast<const bf16x8*>(&Vb[((size_t)(64 + kc) * 64 + lane) * 8]);
    ac0 = __builtin_amdgcn_mfma_f32_16x16x32_bf16(a, b0, ac0, 0, 0, 0);
    ac1 = __builtin_amdgcn_mfma_f32_16x16x32_bf16(a, b1, ac1, 0, 0, 0);
    ac2 = __builtin_amdgcn_mfma_f32_16x16x32_bf16(a, b2, ac2, 0, 0, 0);
  }
  #pragma unroll
  for (int r = 0; r < 4; r++){
    int n = n0 + ks * 4 + r;
    float* zp = Z4 + (size_t)n * ZS4 + kh * 48;
    zp[ 0 + row] = ac0[r];                  // exactly-once plain stores (no atomics)
    zp[16 + row] = ac1[r];
    zp[32 + row] = ac2[r];
  }
}

// ---------- kernel 3: layer-1 fused exp + weighted accumulate (sums 4 slices) ----------
__global__ void edge1(const int* __restrict__ ei, const float* __restrict__ Z4,
                      float* __restrict__ den1, float* __restrict__ a0,
                      float* __restrict__ a1, float* __restrict__ ad){
  int t = blockIdx.x * blockDim.x + threadIdx.x;
  if (t >= ET_ * H_) return;
  int e = t >> 3, h = t & 7;
  int s = eSRC(ei, e), d = eDST(ei, e);
  const float* zs = Z4 + (size_t)s * ZS4;
  const float* zd = Z4 + (size_t)d * ZS4;
  float zsh = 0.f, zdh = 0.f, z0 = 0.f, z1 = 0.f, zdd = 0.f;
  #pragma unroll
  for (int k = 0; k < KSPLIT; k++){
    int o = k * 48;
    zsh += zs[o + h];
    zdh += zd[o + 8 + h];
    z0  += zs[o + 16 + h];
    z1  += zs[o + 24 + h];
    zdd += zs[o + 32 + h];
  }
  float ev = expf(lrelu(zsh + zdh));
  int o = d * 8 + h;
  atomicAdd(&den1[o], ev);
  atomicAdd(&a0[o], ev * z0);
  atomicAdd(&a1[o], ev * z1);
  atomicAdd(&ad[o], ev * zdd);
}

// ---------- kernel 4: layer-2 fused (per-edge recompute of node mids) ----------
__global__ void edge2(const int* __restrict__ ei, const float* __restrict__ den1,
                      const float* __restrict__ a0, const float* __restrict__ a1,
                      const float* __restrict__ ad, const float* __restrict__ cb,
                      const float* __restrict__ a2s,
                      float* __restrict__ den2, float* __restrict__ o0,
                      float* __restrict__ o1){
  int e = blockIdx.x * blockDim.x + threadIdx.x;
  if (e >= ET_) return;
  int s = eSRC(ei, e), d = eDST(ei, e);
  float4 dsa = *reinterpret_cast<const float4*>(den1 + (size_t)s * 8);
  float4 dsb = *reinterpret_cast<const float4*>(den1 + (size_t)s * 8 + 4);
  float4 a0a = *reinterpret_cast<const float4*>(a0 + (size_t)s * 8);
  float4 a0b = *reinterpret_cast<const float4*>(a0 + (size_t)s * 8 + 4);
  float4 a1a = *reinterpret_cast<const float4*>(a1 + (size_t)s * 8);
  float4 a1b = *reinterpret_cast<const float4*>(a1 + (size_t)s * 8 + 4);
  float i0 = 1.f/(dsa.x+1e-16f), i1 = 1.f/(dsa.y+1e-16f);
  float i2 = 1.f/(dsa.z+1e-16f), i3 = 1.f/(dsa.w+1e-16f);
  float i4 = 1.f/(dsb.x+1e-16f), i5 = 1.f/(dsb.y+1e-16f);
  float i6 = 1.f/(dsb.z+1e-16f), i7 = 1.f/(dsb.w+1e-16f);
  float v0 = cb[0] + a0a.x*i0 + a0a.y*i1 + a0a.z*i2 + a0a.w*i3
                   + a0b.x*i4 + a0b.y*i5 + a0b.z*i6 + a0b.w*i7;
  float v1 = cb[1] + a1a.x*i0 + a1a.y*i1 + a1a.z*i2 + a1a.w*i3
                   + a1b.x*i4 + a1b.y*i5 + a1b.z*i6 + a1b.w*i7;
  float4 dda = *reinterpret_cast<const float4*>(den1 + (size_t)d * 8);
  float4 ddb = *reinterpret_cast<const float4*>(den1 + (size_t)d * 8 + 4);
  float4 ada = *reinterpret_cast<const float4*>(ad + (size_t)d * 8);
  float4 adb = *reinterpret_cast<const float4*>(ad + (size_t)d * 8 + 4);
  float vd = cb[2] + ada.x/(dda.x+1e-16f) + ada.y/(dda.y+1e-16f)
                   + ada.z/(dda.z+1e-16f) + ada.w/(dda.w+1e-16f)
                   + adb.x/(ddb.x+1e-16f) + adb.y/(ddb.y+1e-16f)
                   + adb.z/(ddb.z+1e-16f) + adb.w/(ddb.w+1e-16f);
  float als = v0 * a2s[0] + v1 * a2s[1];
  float ev = expf(lrelu(als + vd));
  atomicAdd(&den2[d], ev);
  atomicAdd(&o0[d], ev * v0);
  atomicAdd(&o1[d], ev * v1);
}

// ---------- kernel 5: final division + bias -> out ----------
__global__ void node_out(const float* __restrict__ den2, const float* __restrict__ o0,
                         const float* __restrict__ o1, const float* __restrict__ b2,
                         float* __restrict__ out){
  int n = blockIdx.x * blockDim.x + threadIdx.x;
  if (n >= N_) return;
  float inv = 1.f / (den2[n] + 1e-16f);
  out[2 * n]     = o0[n] * inv + b2[0];
  out[2 * n + 1] = o1[n] * inv + b2[1];
}

// ---------- host ----------
extern "C" void kernel_launch(void* const* d_in, const int* in_sizes, int n_in,
                              void* d_out, int out_size, void* d_ws, size_t ws_size,
                              hipStream_t stream){
  const float* x   = (const float*)d_in[0];
  const int*   ei  = (const int*)  d_in[1];
  const float* W1s = (const float*)d_in[2];
  const float* W1d = (const float*)d_in[3];
  const float* a1s = (const float*)d_in[4];
  const float* a1d = (const float*)d_in[5];
  const float* b1  = (const float*)d_in[6];
  const float* W2s = (const float*)d_in[7];
  const float* W2d = (const float*)d_in[8];
  const float* a2s = (const float*)d_in[9];
  const float* a2d = (const float*)d_in[10];
  const float* b2  = (const float*)d_in[11];
  float* out = (float*)d_out;

  char* p = (char*)d_ws;
  auto alloc = [&](size_t bytes) -> void* {
    void* r = (void*)p;
    p += (bytes + 255) & ~(size_t)255;
    return r;
  };
  float* Z4 = (float*)alloc((size_t)N_ * ZS4 * 4);   // 12 MB, fully overwritten -> no zeroing
  // ---- contiguous zero region ----
  float* den1  = (float*)alloc((size_t)N_ * H_ * 4); // 512 KB
  float* a0    = (float*)alloc((size_t)N_ * H_ * 4);
  float* a1    = (float*)alloc((size_t)N_ * H_ * 4);
  float* ad    = (float*)alloc((size_t)N_ * H_ * 4);
  float* den2  = (float*)alloc((size_t)N_ * 4);      // 64 KB
  float* o0    = (float*)alloc((size_t)N_ * 4);
  float* o1    = (float*)alloc((size_t)N_ * 4);
  // ---- end zero region ----
  unsigned short* Vb = (unsigned short*)alloc((size_t)3 * 32 * 64 * 8 * 2); // 96 KB
  float* cb    = (float*)alloc(256);

  size_t zrBytes = (size_t)((char*)Vb - (char*)den1);
  int n16 = (int)(zrBytes / 16);
  int nzb = (n16 + 255) / 256;

  prep<<<dim3(NVB + 1 + nzb), dim3(256), 0, stream>>>(W1s, W1d, a1s, a1d, W2s, W2d,
                                                      a2d, b1, Vb, cb, (uint4*)den1, n16);
  node_mfma<<<dim3(N_ / 16, KSPLIT), dim3(64), 0, stream>>>(x, Vb, Z4);
  edge1<<<dim3(ET_ * H_ / 256), dim3(256), 0, stream>>>(ei, Z4, den1, a0, a1, ad);
  edge2<<<dim3(ET_ / 256), dim3(256), 0, stream>>>(ei, den1, a0, a1, ad, cb, a2s,
                                                   den2, o0, o1);
  node_out<<<dim3(N_ / 256), dim3(256), 0, stream>>>(den2, o0, o1, b2, out);
}

// Round 12
// 66.245 us; speedup vs baseline: 8.1649x; 1.1319x over previous
//
#include <hip/hip_runtime.h>
#include <cstdint>
#include <cstddef>

#define DEV __device__ __forceinline__

typedef __attribute__((ext_vector_type(8))) short bf16x8;
typedef __attribute__((ext_vector_type(4))) float f32x4;

constexpr int N_  = 16384;
constexpr int D_  = 1024;
constexpr int E_  = 65536;
constexpr int ET_ = E_ + N_;   // edges incl. self loops
constexpr int H_  = 8;
constexpr int C_  = 512;
constexpr int F_  = 4096;      // H_*C_
constexpr int KSPLIT = 4;
constexpr int ZS4 = KSPLIT * 48;  // per-node: 4 slices x [al_s 0..7|al_d 8..15|z0|z1|zd|pad]
constexpr int NVB = 2048;      // V-build blocks in prep
constexpr int NMB = (N_ / 16) * KSPLIT;  // 4096 mfma blocks

// ---------- helpers ----------
DEV unsigned short f2bf(float f){
  unsigned u = __float_as_uint(f);
  unsigned r = u + 0x7FFFu + ((u >> 16) & 1u); // RNE
  return (unsigned short)(r >> 16);
}
DEV float lrelu(float x){ return x >= 0.f ? x : 0.2f * x; }
DEV float waveSum(float v){
  #pragma unroll
  for (int o = 32; o > 0; o >>= 1) v += __shfl_xor(v, o);
  return v;
}
DEV int eSRC(const int* ei, int e){ return e < E_ ? ei[e]      : e - E_; }
DEV int eDST(const int* ei, int e){ return e < E_ ? ei[E_ + e] : e - E_; }

// ---------- kernel 1: prep = build V (MFMA-B-frag) + cb ----------
// col jj of V: jj=h: W1s_h.a1s[h] | 8+h: W1d_h.a1d[h] | 16+h: W1s_h.W2s[:,0]
//              24+h: W1s_h.W2s[:,1] | 32+h: W1s_h.wd2  (wd2 inline from W2d)
// Vb[((tt*32+kc)*64 + ks*16 + j)*8 + i], tt=jj>>4, j=jj&15, kc=d>>5, ks=(d>>3)&3, i=d&7
__global__ __launch_bounds__(256) void prep(
    const float* __restrict__ W1s, const float* __restrict__ W1d,
    const float* __restrict__ a1s, const float* __restrict__ a1d,
    const float* __restrict__ W2s, const float* __restrict__ W2d,
    const float* __restrict__ a2d, const float* __restrict__ b1,
    unsigned short* __restrict__ Vb, float* __restrict__ cb){
  int t = threadIdx.x;
  int bx = blockIdx.x;
  if (bx < NVB){
    int id = bx * 4 + (t >> 6);            // 0..8191
    int lane = t & 63;
    int d = id >> 3, h = id & 7;
    float a2d0 = a2d[0], a2d1 = a2d[1];
    float sa = 0.f, sb = 0.f, s0 = 0.f, s1 = 0.f, sd = 0.f;
    #pragma unroll
    for (int i = 0; i < C_ / 64; i++){
      int c = i * 64 + lane;
      int gc = h * C_ + c;
      float ws  = W1s[(size_t)d * F_ + gc];
      float wdv = W1d[(size_t)d * F_ + gc];
      sa += ws * a1s[gc]; sb += wdv * a1d[gc];
      float2 w2 = *reinterpret_cast<const float2*>(W2s + (size_t)gc * 2);
      float2 wx = *reinterpret_cast<const float2*>(W2d + (size_t)gc * 2);
      s0 += ws * w2.x; s1 += ws * w2.y;
      sd += ws * (wx.x * a2d0 + wx.y * a2d1);
    }
    sa = waveSum(sa); sb = waveSum(sb);
    s0 = waveSum(s0); s1 = waveSum(s1); sd = waveSum(sd);
    if (lane == 0){
      int kc = d >> 5, ks = (d >> 3) & 3, ii = d & 7;
      auto put = [&](int jj, float v){
        int tt = jj >> 4, j = jj & 15;
        Vb[((size_t)(tt * 32 + kc) * 64 + ks * 16 + j) * 8 + ii] = f2bf(v);
      };
      put(h, sa); put(8 + h, sb); put(16 + h, s0); put(24 + h, s1); put(32 + h, sd);
    }
  } else {
    // cb = (b1.W2s[:,0], b1.W2s[:,1], b1.wd2)
    __shared__ float red[3][4];
    int w = t >> 6, lane = t & 63;
    float a2d0 = a2d[0], a2d1 = a2d[1];
    float p0 = 0.f, p1 = 0.f, pd = 0.f;
    for (int k = t; k < F_; k += 256){
      float b = b1[k];
      float2 w2 = *reinterpret_cast<const float2*>(W2s + (size_t)k * 2);
      float2 wx = *reinterpret_cast<const float2*>(W2d + (size_t)k * 2);
      p0 += b * w2.x; p1 += b * w2.y; pd += b * (wx.x * a2d0 + wx.y * a2d1);
    }
    p0 = waveSum(p0); p1 = waveSum(p1); pd = waveSum(pd);
    if (lane == 0){ red[0][w] = p0; red[1][w] = p1; red[2][w] = pd; }
    __syncthreads();
    if (t == 0){
      cb[0] = red[0][0] + red[0][1] + red[0][2] + red[0][3];
      cb[1] = red[1][0] + red[1][1] + red[1][2] + red[1][3];
      cb[2] = red[2][0] + red[2][1] + red[2][2] + red[2][3];
    }
  }
}

// ---------- kernel 2: Z4[n][kh][0..47] = x[n] @ V (plain stores) + zero region ----------
__global__ __launch_bounds__(64) void node_mfma(const float* __restrict__ X,
                                                const unsigned short* __restrict__ Vb,
                                                float* __restrict__ Z4,
                                                uint4* __restrict__ zr, int n16){
  int bx = blockIdx.x;
  int lane = threadIdx.x;
  if (bx >= NMB){
    // zero the accumulator region (den1/a0/a1/ad/den2/o0/o1) — consumed only
    // after this kernel's boundary, runs concurrent with the BW-bound mfma blocks
    int i = (bx - NMB) * 64 + lane;
    if (i < n16){ uint4 z = {0u,0u,0u,0u}; zr[i] = z; }
    return;
  }
  int n0 = (bx >> 2) * 16;
  int kh = bx & 3;                           // 0..KSPLIT-1
  int row = lane & 15, ks = lane >> 4;
  f32x4 ac0 = {0.f,0.f,0.f,0.f}, ac1 = ac0, ac2 = ac0;
  const float* xp = X + (size_t)(n0 + row) * D_ + ks * 8;
  constexpr int KC = 32 / KSPLIT;
  #pragma unroll 2
  for (int kk = 0; kk < KC; kk++){
    int kc = kh * KC + kk;
    float4 xa = *reinterpret_cast<const float4*>(xp + kc * 32);
    float4 xb = *reinterpret_cast<const float4*>(xp + kc * 32 + 4);
    bf16x8 a;
    a[0] = (short)f2bf(xa.x); a[1] = (short)f2bf(xa.y);
    a[2] = (short)f2bf(xa.z); a[3] = (short)f2bf(xa.w);
    a[4] = (short)f2bf(xb.x); a[5] = (short)f2bf(xb.y);
    a[6] = (short)f2bf(xb.z); a[7] = (short)f2bf(xb.w);
    bf16x8 b0 = *reinterpret_cast<const bf16x8*>(&Vb[((size_t)( 0 + kc) * 64 + lane) * 8]);
    bf16x8 b1 = *reinterpret_cast<const bf16x8*>(&Vb[((size_t)(32 + kc) * 64 + lane) * 8]);
    bf16x8 b2 = *reinterpret_cast<const bf16x8*>(&Vb[((size_t)(64 + kc) * 64 + lane) * 8]);
    ac0 = __builtin_amdgcn_mfma_f32_16x16x32_bf16(a, b0, ac0, 0, 0, 0);
    ac1 = __builtin_amdgcn_mfma_f32_16x16x32_bf16(a, b1, ac1, 0, 0, 0);
    ac2 = __builtin_amdgcn_mfma_f32_16x16x32_bf16(a, b2, ac2, 0, 0, 0);
  }
  #pragma unroll
  for (int r = 0; r < 4; r++){
    int n = n0 + ks * 4 + r;
    float* zp = Z4 + (size_t)n * ZS4 + kh * 48;
    zp[ 0 + row] = ac0[r];                  // exactly-once plain stores (no atomics)
    zp[16 + row] = ac1[r];
    zp[32 + row] = ac2[r];
  }
}

// ---------- kernel 3: layer-1 fused exp + weighted accumulate (sums 4 slices) ----------
__global__ void edge1(const int* __restrict__ ei, const float* __restrict__ Z4,
                      float* __restrict__ den1, float* __restrict__ a0,
                      float* __restrict__ a1, float* __restrict__ ad){
  int t = blockIdx.x * blockDim.x + threadIdx.x;
  if (t >= ET_ * H_) return;
  int e = t >> 3, h = t & 7;
  int s = eSRC(ei, e), d = eDST(ei, e);
  const float* zs = Z4 + (size_t)s * ZS4;
  const float* zd = Z4 + (size_t)d * ZS4;
  float zsh = 0.f, zdh = 0.f, z0 = 0.f, z1 = 0.f, zdd = 0.f;
  #pragma unroll
  for (int k = 0; k < KSPLIT; k++){
    int o = k * 48;
    zsh += zs[o + h];
    zdh += zd[o + 8 + h];
    z0  += zs[o + 16 + h];
    z1  += zs[o + 24 + h];
    zdd += zs[o + 32 + h];
  }
  float ev = expf(lrelu(zsh + zdh));
  int o = d * 8 + h;
  atomicAdd(&den1[o], ev);
  atomicAdd(&a0[o], ev * z0);
  atomicAdd(&a1[o], ev * z1);
  atomicAdd(&ad[o], ev * zdd);
}

// ---------- kernel 4: layer-2 fused (per-edge recompute of node mids) ----------
__global__ void edge2(const int* __restrict__ ei, const float* __restrict__ den1,
                      const float* __restrict__ a0, const float* __restrict__ a1,
                      const float* __restrict__ ad, const float* __restrict__ cb,
                      const float* __restrict__ a2s,
                      float* __restrict__ den2, float* __restrict__ o0,
                      float* __restrict__ o1){
  int e = blockIdx.x * blockDim.x + threadIdx.x;
  if (e >= ET_) return;
  int s = eSRC(ei, e), d = eDST(ei, e);
  float4 dsa = *reinterpret_cast<const float4*>(den1 + (size_t)s * 8);
  float4 dsb = *reinterpret_cast<const float4*>(den1 + (size_t)s * 8 + 4);
  float4 a0a = *reinterpret_cast<const float4*>(a0 + (size_t)s * 8);
  float4 a0b = *reinterpret_cast<const float4*>(a0 + (size_t)s * 8 + 4);
  float4 a1a = *reinterpret_cast<const float4*>(a1 + (size_t)s * 8);
  float4 a1b = *reinterpret_cast<const float4*>(a1 + (size_t)s * 8 + 4);
  float i0 = 1.f/(dsa.x+1e-16f), i1 = 1.f/(dsa.y+1e-16f);
  float i2 = 1.f/(dsa.z+1e-16f), i3 = 1.f/(dsa.w+1e-16f);
  float i4 = 1.f/(dsb.x+1e-16f), i5 = 1.f/(dsb.y+1e-16f);
  float i6 = 1.f/(dsb.z+1e-16f), i7 = 1.f/(dsb.w+1e-16f);
  float v0 = cb[0] + a0a.x*i0 + a0a.y*i1 + a0a.z*i2 + a0a.w*i3
                   + a0b.x*i4 + a0b.y*i5 + a0b.z*i6 + a0b.w*i7;
  float v1 = cb[1] + a1a.x*i0 + a1a.y*i1 + a1a.z*i2 + a1a.w*i3
                   + a1b.x*i4 + a1b.y*i5 + a1b.z*i6 + a1b.w*i7;
  float4 dda = *reinterpret_cast<const float4*>(den1 + (size_t)d * 8);
  float4 ddb = *reinterpret_cast<const float4*>(den1 + (size_t)d * 8 + 4);
  float4 ada = *reinterpret_cast<const float4*>(ad + (size_t)d * 8);
  float4 adb = *reinterpret_cast<const float4*>(ad + (size_t)d * 8 + 4);
  float vd = cb[2] + ada.x/(dda.x+1e-16f) + ada.y/(dda.y+1e-16f)
                   + ada.z/(dda.z+1e-16f) + ada.w/(dda.w+1e-16f)
                   + adb.x/(ddb.x+1e-16f) + adb.y/(ddb.y+1e-16f)
                   + adb.z/(ddb.z+1e-16f) + adb.w/(ddb.w+1e-16f);
  float als = v0 * a2s[0] + v1 * a2s[1];
  float ev = expf(lrelu(als + vd));
  atomicAdd(&den2[d], ev);
  atomicAdd(&o0[d], ev * v0);
  atomicAdd(&o1[d], ev * v1);
}

// ---------- kernel 5: final division + bias -> out ----------
__global__ void node_out(const float* __restrict__ den2, const float* __restrict__ o0,
                         const float* __restrict__ o1, const float* __restrict__ b2,
                         float* __restrict__ out){
  int n = blockIdx.x * blockDim.x + threadIdx.x;
  if (n >= N_) return;
  float inv = 1.f / (den2[n] + 1e-16f);
  out[2 * n]     = o0[n] * inv + b2[0];
  out[2 * n + 1] = o1[n] * inv + b2[1];
}

// ---------- host ----------
extern "C" void kernel_launch(void* const* d_in, const int* in_sizes, int n_in,
                              void* d_out, int out_size, void* d_ws, size_t ws_size,
                              hipStream_t stream){
  const float* x   = (const float*)d_in[0];
  const int*   ei  = (const int*)  d_in[1];
  const float* W1s = (const float*)d_in[2];
  const float* W1d = (const float*)d_in[3];
  const float* a1s = (const float*)d_in[4];
  const float* a1d = (const float*)d_in[5];
  const float* b1  = (const float*)d_in[6];
  const float* W2s = (const float*)d_in[7];
  const float* W2d = (const float*)d_in[8];
  const float* a2s = (const float*)d_in[9];
  const float* a2d = (const float*)d_in[10];
  const float* b2  = (const float*)d_in[11];
  float* out = (float*)d_out;

  char* p = (char*)d_ws;
  auto alloc = [&](size_t bytes) -> void* {
    void* r = (void*)p;
    p += (bytes + 255) & ~(size_t)255;
    return r;
  };
  float* Z4 = (float*)alloc((size_t)N_ * ZS4 * 4);   // 12 MB, fully overwritten -> no zeroing
  // ---- contiguous zero region (zeroed inside node_mfma dispatch) ----
  float* den1  = (float*)alloc((size_t)N_ * H_ * 4); // 512 KB
  float* a0    = (float*)alloc((size_t)N_ * H_ * 4);
  float* a1    = (float*)alloc((size_t)N_ * H_ * 4);
  float* ad    = (float*)alloc((size_t)N_ * H_ * 4);
  float* den2  = (float*)alloc((size_t)N_ * 4);      // 64 KB
  float* o0    = (float*)alloc((size_t)N_ * 4);
  float* o1    = (float*)alloc((size_t)N_ * 4);
  // ---- end zero region ----
  unsigned short* Vb = (unsigned short*)alloc((size_t)3 * 32 * 64 * 8 * 2); // 96 KB
  float* cb    = (float*)alloc(256);

  size_t zrBytes = (size_t)((char*)Vb - (char*)den1);
  int n16 = (int)(zrBytes / 16);
  int nzb = (n16 + 63) / 64;

  prep<<<dim3(NVB + 1), dim3(256), 0, stream>>>(W1s, W1d, a1s, a1d, W2s, W2d,
                                                a2d, b1, Vb, cb);
  node_mfma<<<dim3(NMB + nzb), dim3(64), 0, stream>>>(x, Vb, Z4, (uint4*)den1, n16);
  edge1<<<dim3(ET_ * H_ / 256), dim3(256), 0, stream>>>(ei, Z4, den1, a0, a1, ad);
  edge2<<<dim3(ET_ / 256), dim3(256), 0, stream>>>(ei, den1, a0, a1, ad, cb, a2s,
                                                   den2, o0, o1);
  node_out<<<dim3(N_ / 256), dim3(256), 0, stream>>>(den2, o0, o1, b2, out);
}